// Round 1
// baseline (459.559 us; speedup 1.0000x reference)
//
#include <hip/hip_runtime.h>

// Spatial_15968688406784: masked 4x4 block-sum -> gate -> gated copy.
// N=64, C=64, H_IN=110, H_PAD=112, P=4.
// One thread per 4x4 pooled tile: 28x28 tiles/plane, 4096 planes.

#define HIN   110
#define HPAD  112
#define PTILE 28            // pooled tiles per dim
#define TILES (PTILE*PTILE) // 784
#define PLANE_X (HIN*HIN)   // 12100
#define PLANE_M (HPAD*HPAD) // 12544
#define NPLANES 4096
#define TOTAL_TILES (NPLANES*TILES) // 3,211,264 = 12544*256

__global__ __launch_bounds__(256) void spatial_gate_kernel(
    const float* __restrict__ x,
    const float* __restrict__ mask,
    float* __restrict__ out)
{
    unsigned gid = blockIdx.x * 256u + threadIdx.x;
    // grid exactly covers TOTAL_TILES; guard anyway (cheap, uniform)
    if (gid >= TOTAL_TILES) return;

    unsigned plane = gid / TILES;
    unsigned t     = gid - plane * TILES;
    unsigned pr    = t / PTILE;
    unsigned pc    = t - pr * PTILE;

    const float* xp = x    + (size_t)plane * PLANE_X;
    const float* mp = mask + (size_t)plane * PLANE_M;
    float*       op = out  + (size_t)plane * PLANE_X;

    const int  col0   = (int)pc * 4;
    const bool full_c = (pc < PTILE - 1); // pc==27 -> cols 108..111, only 108,109 valid

    float xv[4][4];
    float total = 0.0f;

    #pragma unroll
    for (int r = 0; r < 4; ++r) {
        int row = (int)pr * 4 + r;
        float x0 = 0.f, x1 = 0.f, x2 = 0.f, x3 = 0.f;
        float p0 = 0.f, p1 = 0.f, p2 = 0.f, p3 = 0.f;
        if (row < HIN) {
            const float* xr = xp + row * HIN + col0;
            float2 a = *(const float2*)xr;          // 8B-aligned always
            x0 = a.x; x1 = a.y;
            if (full_c) {
                float2 bq = *(const float2*)(xr + 2);
                x2 = bq.x; x3 = bq.y;
            }
            float4 mv = *(const float4*)(mp + row * HPAD + col0); // 16B-aligned
            // products with explicit rounding (no FMA contraction) so the
            // pooled sum bit-matches numpy's sequential reduction
            p0 = __fmul_rn(x0, mv.x);
            p1 = __fmul_rn(x1, mv.y);
            p2 = __fmul_rn(x2, mv.z);
            p3 = __fmul_rn(x3, mv.w);
        }
        // numpy order: reduce innermost (cols) sequentially...
        float rs = __fadd_rn(__fadd_rn(__fadd_rn(p0, p1), p2), p3);
        // ...then rows sequentially (starting from +0.0f is exact)
        total = __fadd_rn(total, rs);
        xv[r][0] = x0; xv[r][1] = x1; xv[r][2] = x2; xv[r][3] = x3;
    }

    const float b = (total > 0.0f) ? 1.0f : 0.0f;

    #pragma unroll
    for (int r = 0; r < 4; ++r) {
        int row = (int)pr * 4 + r;
        if (row < HIN) {
            float* orow = op + row * HIN + col0;
            float2 s0; s0.x = xv[r][0] * b; s0.y = xv[r][1] * b;
            *(float2*)orow = s0;
            if (full_c) {
                float2 s1; s1.x = xv[r][2] * b; s1.y = xv[r][3] * b;
                *(float2*)(orow + 2) = s1;
            }
        }
    }
}

extern "C" void kernel_launch(void* const* d_in, const int* in_sizes, int n_in,
                              void* d_out, int out_size, void* d_ws, size_t ws_size,
                              hipStream_t stream) {
    const float* x    = (const float*)d_in[0];
    const float* mask = (const float*)d_in[1];
    // d_in[2] is p_size == 4, baked into the kernel constants.
    float* out = (float*)d_out;

    dim3 grid(TOTAL_TILES / 256); // 12544
    dim3 block(256);
    hipLaunchKernelGGL(spatial_gate_kernel, grid, block, 0, stream, x, mask, out);
}

// Round 2
// 451.289 us; speedup vs baseline: 1.0183x; 1.0183x over previous
//
#include <hip/hip_runtime.h>

// Spatial_15968688406784: masked 4x4 block-sum -> gate -> gated copy.
// N=64, C=64, H_IN=110, H_PAD=112, P=4.
//
// Round 2 strategy: per-block quarter-plane LDS staging so that EVERY global
// access is a contiguous, 16B-aligned float4 (dwordx4) — round 1 was VMEM
// instruction-issue bound with 8B strided accesses (2.6 TB/s, 33% peak).
//
// Block = 256 threads handles 7 tile-rows (28 x-rows) of one plane:
//   x region    : 28*110 = 3080 floats, contiguous in global, 16B-aligned
//   mask region : 28*112 = 3136 floats, contiguous in global, 16B-aligned
//   out region  : same as x region
// Grid = 4096 planes * 4 quarters = 16384 blocks.

#define HIN     110
#define HPAD    112
#define PLANE_X 12100           // 110*110
#define PLANE_M 12544           // 112*112
#define QROWS   28              // x rows per block (7 tile-rows)
#define QX      (QROWS*HIN)     // 3080
#define QX4     (QX/4)          // 770
#define QM      (QROWS*HPAD)    // 3136
#define QM4     (QM/4)          // 784
#define NTILES  196             // 7*28 pooled tiles per block

__global__ __launch_bounds__(256) void spatial_gate_kernel(
    const float* __restrict__ x,
    const float* __restrict__ mask,
    float* __restrict__ out)
{
    __shared__ __align__(16) float sx[QX];   // 12320 B
    __shared__ __align__(16) float sm[QM];   // 12544 B
    __shared__ float sg[NTILES];             //   784 B  -> 25648 B total, 6 blk/CU

    const int tid = threadIdx.x;
    const unsigned blk   = blockIdx.x;
    const unsigned plane = blk >> 2;
    const unsigned q     = blk & 3;
    const int r0    = (int)q * QROWS;                       // 0,28,56,84
    const int vrows = (r0 + QROWS <= HIN) ? QROWS : (HIN - r0); // 28,28,28,26
    const int nval  = vrows * HIN;                          // 3080 or 2860
    const int nval4 = nval >> 2;                            // 770 or 715

    const float4* __restrict__ xg = (const float4*)(x    + (size_t)plane*PLANE_X + (size_t)r0*HIN);
    const float4* __restrict__ mg = (const float4*)(mask + (size_t)plane*PLANE_M + (size_t)r0*HPAD);
    float4*       __restrict__ og = (float4*)      (out  + (size_t)plane*PLANE_X + (size_t)r0*HIN);
    float4* sx4 = (float4*)sx;
    float4* sm4 = (float4*)sm;

    // ---- stage: contiguous float4 global->LDS ----
    for (int i = tid; i < nval4; i += 256) sx4[i] = xg[i];
    // zero-fill the invalid tail rows (only q==3: rows 110,111 of the pad)
    for (int i = nval4 + tid; i < QX4; i += 256) sx4[i] = make_float4(0.f,0.f,0.f,0.f);
    for (int i = tid; i < QM4; i += 256) sm4[i] = mg[i];
    __syncthreads();

    // ---- gate compute: one thread per 4x4 tile ----
    if (tid < NTILES) {
        const int tr   = tid / 28;
        const int tc   = tid - tr * 28;
        const int col0 = tc * 4;
        float total = 0.f;
        #pragma unroll
        for (int r = 0; r < 4; ++r) {
            const int lr = tr * 4 + r;
            const float* xr = sx + lr * HIN;
            const float* mr = sm + lr * HPAD + col0;
            float p[4];
            #pragma unroll
            for (int j = 0; j < 4; ++j) {
                const int c  = col0 + j;
                const int cs = (c < HIN) ? c : 0;   // safe in-bounds index
                float xv = xr[cs];
                xv = (c < HIN) ? xv : 0.f;          // cols 110,111 are pad -> 0
                // explicit rounding: no FMA contraction, match numpy bitwise
                p[j] = __fmul_rn(xv, mr[j]);
            }
            // numpy order: cols sequential, then rows sequential
            const float rs = __fadd_rn(__fadd_rn(__fadd_rn(p[0], p[1]), p[2]), p[3]);
            total = __fadd_rn(total, rs);
        }
        sg[tid] = (total > 0.f) ? 1.f : 0.f;
    }
    __syncthreads();

    // ---- gated writeback: contiguous float4 LDS->global ----
    for (int i4 = tid; i4 < nval4; i4 += 256) {
        const float4 v = sx4[i4];
        const int i = i4 << 2;
        float o[4];
        float e[4] = {v.x, v.y, v.z, v.w};
        #pragma unroll
        for (int j = 0; j < 4; ++j) {
            const int idx = i + j;
            const int row = idx / HIN;            // const divisor -> mulhi
            const int col = idx - row * HIN;
            o[j] = e[j] * sg[(row >> 2) * 28 + (col >> 2)];
        }
        og[i4] = make_float4(o[0], o[1], o[2], o[3]);
    }
}

extern "C" void kernel_launch(void* const* d_in, const int* in_sizes, int n_in,
                              void* d_out, int out_size, void* d_ws, size_t ws_size,
                              hipStream_t stream) {
    const float* x    = (const float*)d_in[0];
    const float* mask = (const float*)d_in[1];
    // d_in[2] is p_size == 4, baked into the kernel constants.
    float* out = (float*)d_out;

    dim3 grid(4096u * 4u);   // one block per quarter-plane
    dim3 block(256);
    hipLaunchKernelGGL(spatial_gate_kernel, grid, block, 0, stream, x, mask, out);
}

// Round 4
// 438.688 us; speedup vs baseline: 1.0476x; 1.0287x over previous
//
#include <hip/hip_runtime.h>

// Spatial_15968688406784: masked 4x4 block-sum -> gate -> gated copy.
// N=64, C=64, H_IN=110, H_PAD=112, P=4.
//
// Round 3b: round-2 structure (quarter-plane LDS staging, all-float4 global
// access) + NON-TEMPORAL loads/stores, using a native clang ext_vector_type
// (HIP's float4 struct is rejected by the nontemporal builtins).
// Rationale: R1 (no-LDS, 8B strided) and R2 (LDS, 16B coalesced) both pinned
// at ~154 us => memory-system wall, not instruction issue. out-stream L3
// write-allocations evict restore-resident input lines (598 MB working set
// vs 256 MB L3). NT stores keep out from allocating in L3; NT loads still
// probe L3 but don't thrash on miss.

typedef float f4 __attribute__((ext_vector_type(4)));

#define HIN     110
#define HPAD    112
#define PLANE_X 12100           // 110*110
#define PLANE_M 12544           // 112*112
#define QROWS   28              // x rows per block (7 tile-rows)
#define QX      (QROWS*HIN)     // 3080
#define QX4     (QX/4)          // 770
#define QM      (QROWS*HPAD)    // 3136
#define QM4     (QM/4)          // 784
#define NTILES  196             // 7*28 pooled tiles per block

__global__ __launch_bounds__(256) void spatial_gate_kernel(
    const float* __restrict__ x,
    const float* __restrict__ mask,
    float* __restrict__ out)
{
    __shared__ __align__(16) float sx[QX];   // 12320 B
    __shared__ __align__(16) float sm[QM];   // 12544 B
    __shared__ float sg[NTILES];             //   784 B

    const int tid = threadIdx.x;
    const unsigned blk   = blockIdx.x;
    const unsigned plane = blk >> 2;
    const unsigned q     = blk & 3;
    const int r0    = (int)q * QROWS;                           // 0,28,56,84
    const int vrows = (r0 + QROWS <= HIN) ? QROWS : (HIN - r0); // 28,28,28,26
    const int nval  = vrows * HIN;                              // 3080 or 2860
    const int nval4 = nval >> 2;                                // 770 or 715

    const f4* __restrict__ xg = (const f4*)(x    + (size_t)plane*PLANE_X + (size_t)r0*HIN);
    const f4* __restrict__ mg = (const f4*)(mask + (size_t)plane*PLANE_M + (size_t)r0*HPAD);
    f4*       __restrict__ og = (f4*)      (out  + (size_t)plane*PLANE_X + (size_t)r0*HIN);
    f4* sx4 = (f4*)sx;
    f4* sm4 = (f4*)sm;

    // ---- stage: contiguous float4 global->LDS, non-temporal loads ----
    for (int i = tid; i < nval4; i += 256) sx4[i] = __builtin_nontemporal_load(&xg[i]);
    for (int i = nval4 + tid; i < QX4; i += 256) sx4[i] = (f4){0.f,0.f,0.f,0.f};
    for (int i = tid; i < QM4; i += 256) sm4[i] = __builtin_nontemporal_load(&mg[i]);
    __syncthreads();

    // ---- gate compute: one thread per 4x4 tile ----
    if (tid < NTILES) {
        const int tr   = tid / 28;
        const int tc   = tid - tr * 28;
        const int col0 = tc * 4;
        float total = 0.f;
        #pragma unroll
        for (int r = 0; r < 4; ++r) {
            const int lr = tr * 4 + r;
            const float* xr = sx + lr * HIN;
            const float* mr = sm + lr * HPAD + col0;
            float p[4];
            #pragma unroll
            for (int j = 0; j < 4; ++j) {
                const int c  = col0 + j;
                const int cs = (c < HIN) ? c : 0;   // safe in-bounds index
                float xv = xr[cs];
                xv = (c < HIN) ? xv : 0.f;          // cols 110,111 are pad -> 0
                // explicit rounding: no FMA contraction, match numpy bitwise
                p[j] = __fmul_rn(xv, mr[j]);
            }
            // numpy order: cols sequential, then rows sequential
            const float rs = __fadd_rn(__fadd_rn(__fadd_rn(p[0], p[1]), p[2]), p[3]);
            total = __fadd_rn(total, rs);
        }
        sg[tid] = (total > 0.f) ? 1.f : 0.f;
    }
    __syncthreads();

    // ---- gated writeback: contiguous float4 LDS->global, non-temporal ----
    for (int i4 = tid; i4 < nval4; i4 += 256) {
        const f4 v = sx4[i4];
        const int i = i4 << 2;
        f4 o;
        #pragma unroll
        for (int j = 0; j < 4; ++j) {
            const int idx = i + j;
            const int row = idx / HIN;            // const divisor -> mulhi
            const int col = idx - row * HIN;
            o[j] = v[j] * sg[(row >> 2) * 28 + (col >> 2)];
        }
        __builtin_nontemporal_store(o, &og[i4]);
    }
}

extern "C" void kernel_launch(void* const* d_in, const int* in_sizes, int n_in,
                              void* d_out, int out_size, void* d_ws, size_t ws_size,
                              hipStream_t stream) {
    const float* x    = (const float*)d_in[0];
    const float* mask = (const float*)d_in[1];
    // d_in[2] is p_size == 4, baked into the kernel constants.
    float* out = (float*)d_out;

    dim3 grid(4096u * 4u);   // one block per quarter-plane
    dim3 block(256);
    hipLaunchKernelGGL(spatial_gate_kernel, grid, block, 0, stream, x, mask, out);
}